// Round 9
// baseline (177.397 us; speedup 1.0000x reference)
//
#include <hip/hip_runtime.h>

typedef __attribute__((ext_vector_type(8))) short short8;
typedef __attribute__((ext_vector_type(4))) float f32x4;

#define KFC   131072   // 128*32*32
#define NCLS  1000

__device__ __forceinline__ unsigned short f2bf(float f) {
  union { float f; unsigned u; } v; v.f = f;
  unsigned r = v.u + 0x7FFFu + ((v.u >> 16) & 1u);   // RNE
  return (unsigned short)(r >> 16);
}

// ---------------------------------------------------------------------------
// conv1: x[64,3,128,128] fp32 -> y[64,64,64,64] bf16 NHWC (b,ph,pw,c)
// ---------------------------------------------------------------------------
__global__ __launch_bounds__(256) void conv1_kernel(
    const float* __restrict__ x, const float* __restrict__ w1,
    const float* __restrict__ b1, unsigned short* __restrict__ y) {
  __shared__ float tile[3][34][20];
  const int t = threadIdx.x;
  const int blk = blockIdx.x;                 // b*32 + ty*8 + tx
  const int tx = blk & 7, ty = (blk >> 3) & 3, b = blk >> 5;
  const int ih0 = ty * 32 - 1, iw0 = tx * 16 - 1;

  for (int i = t; i < 3 * 34 * 20; i += 256) {
    int ci = i / 680, rem = i - ci * 680;
    int r = rem / 20, s = rem - r * 20;
    int ih = ih0 + r, iw = iw0 + s;
    bool ok = (s < 18) && ((unsigned)ih < 128u) && ((unsigned)iw < 128u);
    tile[ci][r][s] = ok ? x[(b * 3 + ci) * 16384 + (ih << 7) + iw] : 0.f;
  }
  __syncthreads();

  const int c = t & 63, quad = t >> 6;
  const int qy = quad >> 1, qx = quad & 1;

  float wr[27];
#pragma unroll
  for (int k = 0; k < 27; ++k) wr[k] = w1[c * 27 + k];
  const float bias = b1[c];

  for (int pr = 0; pr < 8; ++pr) {
    float acc0[8], acc1[8];
#pragma unroll
    for (int i = 0; i < 8; ++i) { acc0[i] = 0.f; acc1[i] = 0.f; }

    const int r0 = qy * 16 + 2 * pr;
#pragma unroll
    for (int ci = 0; ci < 3; ++ci) {
#pragma unroll
      for (int r = 0; r < 4; ++r) {
        float rv[12];
        {
          const float* rp = &tile[ci][r0 + r][qx * 8];
#pragma unroll
          for (int v4 = 0; v4 < 3; ++v4) {
            float4 v = *(const float4*)(rp + v4 * 4);
            rv[v4 * 4 + 0] = v.x; rv[v4 * 4 + 1] = v.y;
            rv[v4 * 4 + 2] = v.z; rv[v4 * 4 + 3] = v.w;
          }
        }
        if (r < 3) {
#pragma unroll
          for (int kw = 0; kw < 3; ++kw) {
            float wt = wr[ci * 9 + r * 3 + kw];
#pragma unroll
            for (int w = 0; w < 8; ++w) acc0[w] += rv[w + kw] * wt;
          }
        }
        if (r >= 1) {
#pragma unroll
          for (int kw = 0; kw < 3; ++kw) {
            float wt = wr[ci * 9 + (r - 1) * 3 + kw];
#pragma unroll
            for (int w = 0; w < 8; ++w) acc1[w] += rv[w + kw] * wt;
          }
        }
      }
    }

    const int ph = ty * 16 + qy * 8 + pr;
    const int pwb = tx * 8 + qx * 4;
    unsigned short* dst = y + ((((size_t)b << 6) + ph) << 12) + ((size_t)pwb << 6) + c;
#pragma unroll
    for (int pw = 0; pw < 4; ++pw) {
      float m = fmaxf(fmaxf(acc0[2 * pw], acc0[2 * pw + 1]),
                      fmaxf(acc1[2 * pw], acc1[2 * pw + 1]));
      m = fmaxf(m + bias, 0.f);
      dst[(size_t)pw << 6] = f2bf(m);
    }
  }
}

// ---------------------------------------------------------------------------
// weight reorder for conv2: Bprep[((cg*9+pos)*128 + o)*32 + c] = bf16(w2[o][(cg*32+c)*9 + pos])
// ---------------------------------------------------------------------------
__global__ __launch_bounds__(256) void prep_w2(
    const float* __restrict__ w2, short* __restrict__ Bp) {
  int i = blockIdx.x * 256 + threadIdx.x;   // 73728 total
  int c = i & 31, o = (i >> 5) & 127, pp = i >> 12;
  int cg = pp / 9, pos = pp - cg * 9;
  Bp[i] = (short)f2bf(w2[o * 576 + (cg * 32 + c) * 9 + pos]);
}

// ---------------------------------------------------------------------------
// conv2 implicit-GEMM MFMA: y[64,64,64,64] bf16 NHWC -> A[64,131072] bf16 (flat [128,32,32])
// block = 256 thr (4 waves, 2M x 2N), px tile = 8 conv rows x 16 cols, all 128 o.
// Stage 10x18 x 64ch window ONCE (25.9 KB) -> one barrier pair, then waves
// free-run 9 pos x 2 k-slices. 4 independent blocks/CU cover load latency.
// ---------------------------------------------------------------------------
__global__ __launch_bounds__(256) void conv2_mfma(
    const short* __restrict__ yin, const short* __restrict__ Bp,
    const float* __restrict__ b2, unsigned int* __restrict__ A32) {
  __shared__ short tile[180 * 72];            // [10*18 spatial][64ch + 8 pad]
  const int t = threadIdx.x;
  const int blk = blockIdx.x;                 // b*32 + brow*4 + bcol
  const int bcol = blk & 3, brow = (blk >> 2) & 7, b = blk >> 5;
  const int w = t >> 6, lane = t & 63;
  const int wm = w & 1, wn = w >> 1;          // 2M x 2N wave grid
  const int l15 = lane & 15, lg = lane >> 4;

  const int ih0 = brow * 8 - 1, iw0 = bcol * 16 - 1;

  // stage: 180 px x 8 ch-octets
  for (int i = t; i < 1440; i += 256) {
    int p = i >> 3, q = i & 7;
    int sy = p / 18, sx = p - sy * 18;
    int ih = ih0 + sy, iw = iw0 + sx;
    short8 v = (short8){0, 0, 0, 0, 0, 0, 0, 0};
    if (((unsigned)ih < 64u) && ((unsigned)iw < 64u))
      v = *(const short8*)(yin + ((((size_t)b << 6) + ih) << 12) + ((size_t)iw << 6) + q * 8);
    *(short8*)&tile[p * 72 + q * 8] = v;
  }
  __syncthreads();

  f32x4 acc[4][4];
#pragma unroll
  for (int m = 0; m < 4; ++m)
#pragma unroll
    for (int n = 0; n < 4; ++n) acc[m][n] = (f32x4){0.f, 0.f, 0.f, 0.f};

  const int rbase = wm * 4;
#pragma unroll
  for (int pos = 0; pos < 9; ++pos) {
    const int kh = pos / 3, kw = pos % 3;
#pragma unroll
    for (int ks = 0; ks < 2; ++ks) {
      short8 bf[4];
#pragma unroll
      for (int n = 0; n < 4; ++n)
        bf[n] = *(const short8*)(Bp + ((((ks * 9 + pos) << 7) + (wn * 4 + n) * 16 + l15) << 5) + (lg << 3));
      short8 af[4];
#pragma unroll
      for (int m = 0; m < 4; ++m) {
        int sp = (rbase + m + kh) * 18 + l15 + kw;
        af[m] = *(const short8*)&tile[sp * 72 + ks * 32 + lg * 8];
      }
#pragma unroll
      for (int n = 0; n < 4; ++n)
#pragma unroll
        for (int m = 0; m < 4; ++m)
          acc[m][n] = __builtin_amdgcn_mfma_f32_16x16x32_bf16(af[m], bf[n], acc[m][n], 0, 0, 0);
    }
  }

  // epilogue: bias + relu + 2x2 pool.
  // conv row = brow*8 + wm*4 + mfrag; conv col = lg*4 + j (C layout: row=lg*4+j, col=l15->o)
  const size_t bbase = ((size_t)b << 16);   // u32 units
#pragma unroll
  for (int n = 0; n < 4; ++n) {
    const int o = (wn * 4 + n) * 16 + l15;
    const float bias = b2[o];
#pragma unroll
    for (int mp = 0; mp < 2; ++mp) {
      const int prow = brow * 4 + wm * 2 + mp;
      float v0 = fmaxf(fmaxf(acc[2 * mp][n][0], acc[2 * mp][n][1]),
                       fmaxf(acc[2 * mp + 1][n][0], acc[2 * mp + 1][n][1]));
      float v1 = fmaxf(fmaxf(acc[2 * mp][n][2], acc[2 * mp][n][3]),
                       fmaxf(acc[2 * mp + 1][n][2], acc[2 * mp + 1][n][3]));
      v0 = fmaxf(v0 + bias, 0.f);
      v1 = fmaxf(v1 + bias, 0.f);
      unsigned pk = (unsigned)f2bf(v0) | ((unsigned)f2bf(v1) << 16);
      A32[bbase + (size_t)o * 512 + prow * 16 + bcol * 4 + lg] = pk;
    }
  }
}

// ---------------------------------------------------------------------------
// fc1 MFMA (BW-bound): grid 1024 = 256 kc x 4 nt; K-chunk 512 (4 iters of 128).
// ---------------------------------------------------------------------------
__global__ __launch_bounds__(256) void fc1_mfma(
    const unsigned short* __restrict__ A, const float* __restrict__ W,
    float* __restrict__ P) {
  __shared__ short Wl[64 * 136];
  __shared__ short Al[64 * 136];
  const int t = threadIdx.x;
  const int kc = blockIdx.x >> 2, nt = blockIdx.x & 3;
  const int w = t >> 6, lane = t & 63;
  const int l15 = lane & 15, lg = lane >> 4;
  const int wm = w >> 1, wn = w & 1;

  const int row = t >> 2, q = t & 3;
  const float* wsrc = W + (size_t)(nt * 64 + row) * KFC + kc * 512 + q * 32;
  const unsigned short* asrc = A + (size_t)row * KFC + kc * 512 + q * 32;

  f32x4 acc[2][2];
#pragma unroll
  for (int i = 0; i < 2; ++i)
#pragma unroll
    for (int j = 0; j < 2; ++j) acc[i][j] = (f32x4){0.f, 0.f, 0.f, 0.f};

  f32x4 wreg[8]; short8 areg[4];
#pragma unroll
  for (int i = 0; i < 8; ++i) wreg[i] = *(const f32x4*)(wsrc + i * 4);
#pragma unroll
  for (int i = 0; i < 4; ++i) areg[i] = *(const short8*)(asrc + i * 8);

  for (int it = 0; it < 4; ++it) {
    __syncthreads();
    {
      unsigned* wd = (unsigned*)&Wl[row * 136 + q * 32];
#pragma unroll
      for (int i = 0; i < 8; ++i) {
        f32x4 v = wreg[i];
        wd[i * 2 + 0] = (unsigned)f2bf(v[0]) | ((unsigned)f2bf(v[1]) << 16);
        wd[i * 2 + 1] = (unsigned)f2bf(v[2]) | ((unsigned)f2bf(v[3]) << 16);
      }
      short8* ad = (short8*)&Al[row * 136 + q * 32];
#pragma unroll
      for (int i = 0; i < 4; ++i) ad[i] = areg[i];
    }
    __syncthreads();
    if (it < 3) {
      const float* wp = wsrc + (it + 1) * 128;
      const unsigned short* ap = asrc + (it + 1) * 128;
#pragma unroll
      for (int i = 0; i < 8; ++i) wreg[i] = *(const f32x4*)(wp + i * 4);
#pragma unroll
      for (int i = 0; i < 4; ++i) areg[i] = *(const short8*)(ap + i * 8);
    }
#pragma unroll
    for (int ks = 0; ks < 4; ++ks) {
      short8 af0 = *(const short8*)&Al[(wm * 32 + l15) * 136 + ks * 32 + lg * 8];
      short8 af1 = *(const short8*)&Al[(wm * 32 + 16 + l15) * 136 + ks * 32 + lg * 8];
      short8 bf0 = *(const short8*)&Wl[(wn * 32 + l15) * 136 + ks * 32 + lg * 8];
      short8 bf1 = *(const short8*)&Wl[(wn * 32 + 16 + l15) * 136 + ks * 32 + lg * 8];
      acc[0][0] = __builtin_amdgcn_mfma_f32_16x16x32_bf16(af0, bf0, acc[0][0], 0, 0, 0);
      acc[0][1] = __builtin_amdgcn_mfma_f32_16x16x32_bf16(af0, bf1, acc[0][1], 0, 0, 0);
      acc[1][0] = __builtin_amdgcn_mfma_f32_16x16x32_bf16(af1, bf0, acc[1][0], 0, 0, 0);
      acc[1][1] = __builtin_amdgcn_mfma_f32_16x16x32_bf16(af1, bf1, acc[1][1], 0, 0, 0);
    }
  }

  float* dst = P + (size_t)kc * 16384;
#pragma unroll
  for (int mf = 0; mf < 2; ++mf)
#pragma unroll
    for (int nf = 0; nf < 2; ++nf)
#pragma unroll
      for (int j = 0; j < 4; ++j) {
        int brow = wm * 32 + mf * 16 + lg * 4 + j;
        int o = nt * 64 + wn * 32 + nf * 16 + l15;
        dst[brow * 256 + o] = acc[mf][nf][j];
      }
}

// fc1 partial reduce + bias + relu -> Y[64,256]. 256 blocks, coalesced.
__global__ __launch_bounds__(256) void fc1_reduce_kernel(
    const float* __restrict__ P, const float* __restrict__ fb1,
    float* __restrict__ Y) {
  __shared__ float red[4][64];
  const int t = threadIdx.x;
  const int iq = t & 63, pg = t >> 6;
  const int gidx = blockIdx.x * 64 + iq;
  const float* p0 = P + (size_t)(pg * 64) * 16384 + gidx;
  float s0 = 0, s1 = 0, s2 = 0, s3 = 0;
#pragma unroll
  for (int p = 0; p < 64; p += 4) {
    s0 += p0[(size_t)(p + 0) * 16384];
    s1 += p0[(size_t)(p + 1) * 16384];
    s2 += p0[(size_t)(p + 2) * 16384];
    s3 += p0[(size_t)(p + 3) * 16384];
  }
  red[pg][iq] = (s0 + s1) + (s2 + s3);
  __syncthreads();
  if (pg == 0) {
    float tot = (red[0][iq] + red[1][iq]) + (red[2][iq] + red[3][iq]);
    Y[gidx] = fmaxf(tot + fb1[gidx & 255], 0.f);
  }
}

// fc2: out[64,1000] = Y[64,256] @ W2[1000,256]^T + b2
__global__ __launch_bounds__(256) void fc2_kernel(
    const float* __restrict__ Y, const float* __restrict__ W2,
    const float* __restrict__ b2, float* __restrict__ out) {
  int tid = blockIdx.x * 256 + threadIdx.x;
  if (tid >= 64 * NCLS) return;
  int b = tid / NCLS, n = tid - b * NCLS;
  const float4* yv = (const float4*)(Y + b * 256);
  const float4* wv = (const float4*)(W2 + n * 256);
  float acc = 0.f;
#pragma unroll 8
  for (int f = 0; f < 64; ++f) {
    float4 a = yv[f], w = wv[f];
    acc += a.x * w.x + a.y * w.y + a.z * w.z + a.w * w.w;
  }
  out[tid] = acc + b2[n];
}

// ---------------------------------------------------------------------------
extern "C" void kernel_launch(void* const* d_in, const int* in_sizes, int n_in,
                              void* d_out, int out_size, void* d_ws, size_t ws_size,
                              hipStream_t stream) {
  const float* x   = (const float*)d_in[0];
  const float* w1  = (const float*)d_in[1];
  const float* b1  = (const float*)d_in[2];
  const float* w2  = (const float*)d_in[3];
  const float* b2  = (const float*)d_in[4];
  const float* fw1 = (const float*)d_in[5];
  const float* fb1 = (const float*)d_in[6];
  const float* fw2 = (const float*)d_in[7];
  const float* fb2 = (const float*)d_in[8];
  float* out = (float*)d_out;

  unsigned short* Y1 = (unsigned short*)d_ws;              // conv1 out bf16 NHWC [16777216]
  unsigned short* A16 = Y1 + 16777216;                     // conv2 out bf16 [8388608]
  short* Bp = (short*)(A16 + 8388608);                     // conv2 weights bf16 [73728]
  float* P  = (float*)(Bp + 73728);                        // fc1 partials [256*16384]
  float* Yf = P + 4194304;                                 // fc1 out [16384]

  prep_w2<<<288, 256, 0, stream>>>(w2, Bp);
  conv1_kernel<<<2048, 256, 0, stream>>>(x, w1, b1, Y1);
  conv2_mfma<<<2048, 256, 0, stream>>>((const short*)Y1, Bp, b2, (unsigned int*)A16);
  fc1_mfma<<<1024, 256, 0, stream>>>(A16, fw1, P);
  fc1_reduce_kernel<<<256, 256, 0, stream>>>(P, fb1, Yf);
  fc2_kernel<<<250, 256, 0, stream>>>(Yf, fw2, fb2, out);
}

// Round 10
// 152.248 us; speedup vs baseline: 1.1652x; 1.1652x over previous
//
#include <hip/hip_runtime.h>
#include <hip/hip_bf16.h>

typedef __attribute__((ext_vector_type(8))) short short8;
typedef __attribute__((ext_vector_type(4))) float f32x4;

#define KFC   131072   // 128*32*32
#define NCLS  1000

__device__ __forceinline__ unsigned short f2bf(float f) {
  union { float f; unsigned u; } v; v.f = f;
  unsigned r = v.u + 0x7FFFu + ((v.u >> 16) & 1u);   // RNE
  return (unsigned short)(r >> 16);
}

__device__ __forceinline__ unsigned pk2bf(float a, float b) {
  __hip_bfloat162 h = __float22bfloat162_rn(float2{a, b});
  union { __hip_bfloat162 h; unsigned u; } c; c.h = h;
  return c.u;
}

// ---------------------------------------------------------------------------
// conv1: x[64,3,128,128] fp32 -> y[64,64,64,64] bf16 NHWC (b,ph,pw,c)
// ---------------------------------------------------------------------------
__global__ __launch_bounds__(256) void conv1_kernel(
    const float* __restrict__ x, const float* __restrict__ w1,
    const float* __restrict__ b1, unsigned short* __restrict__ y) {
  __shared__ float tile[3][34][20];
  const int t = threadIdx.x;
  const int blk = blockIdx.x;                 // b*32 + ty*8 + tx
  const int tx = blk & 7, ty = (blk >> 3) & 3, b = blk >> 5;
  const int ih0 = ty * 32 - 1, iw0 = tx * 16 - 1;

  for (int i = t; i < 3 * 34 * 20; i += 256) {
    int ci = i / 680, rem = i - ci * 680;
    int r = rem / 20, s = rem - r * 20;
    int ih = ih0 + r, iw = iw0 + s;
    bool ok = (s < 18) && ((unsigned)ih < 128u) && ((unsigned)iw < 128u);
    tile[ci][r][s] = ok ? x[(b * 3 + ci) * 16384 + (ih << 7) + iw] : 0.f;
  }
  __syncthreads();

  const int c = t & 63, quad = t >> 6;
  const int qy = quad >> 1, qx = quad & 1;

  float wr[27];
#pragma unroll
  for (int k = 0; k < 27; ++k) wr[k] = w1[c * 27 + k];
  const float bias = b1[c];

  for (int pr = 0; pr < 8; ++pr) {
    float acc0[8], acc1[8];
#pragma unroll
    for (int i = 0; i < 8; ++i) { acc0[i] = 0.f; acc1[i] = 0.f; }

    const int r0 = qy * 16 + 2 * pr;
#pragma unroll
    for (int ci = 0; ci < 3; ++ci) {
#pragma unroll
      for (int r = 0; r < 4; ++r) {
        float rv[12];
        {
          const float* rp = &tile[ci][r0 + r][qx * 8];
#pragma unroll
          for (int v4 = 0; v4 < 3; ++v4) {
            float4 v = *(const float4*)(rp + v4 * 4);
            rv[v4 * 4 + 0] = v.x; rv[v4 * 4 + 1] = v.y;
            rv[v4 * 4 + 2] = v.z; rv[v4 * 4 + 3] = v.w;
          }
        }
        if (r < 3) {
#pragma unroll
          for (int kw = 0; kw < 3; ++kw) {
            float wt = wr[ci * 9 + r * 3 + kw];
#pragma unroll
            for (int w = 0; w < 8; ++w) acc0[w] += rv[w + kw] * wt;
          }
        }
        if (r >= 1) {
#pragma unroll
          for (int kw = 0; kw < 3; ++kw) {
            float wt = wr[ci * 9 + (r - 1) * 3 + kw];
#pragma unroll
            for (int w = 0; w < 8; ++w) acc1[w] += rv[w + kw] * wt;
          }
        }
      }
    }

    const int ph = ty * 16 + qy * 8 + pr;
    const int pwb = tx * 8 + qx * 4;
    unsigned short* dst = y + ((((size_t)b << 6) + ph) << 12) + ((size_t)pwb << 6) + c;
#pragma unroll
    for (int pw = 0; pw < 4; ++pw) {
      float m = fmaxf(fmaxf(acc0[2 * pw], acc0[2 * pw + 1]),
                      fmaxf(acc1[2 * pw], acc1[2 * pw + 1]));
      m = fmaxf(m + bias, 0.f);
      dst[(size_t)pw << 6] = f2bf(m);
    }
  }
}

// ---------------------------------------------------------------------------
// weight reorder for conv2: Bprep[((cg*9+pos)*128 + o)*32 + c] = bf16(w2[o][(cg*32+c)*9 + pos])
// ---------------------------------------------------------------------------
__global__ __launch_bounds__(256) void prep_w2(
    const float* __restrict__ w2, short* __restrict__ Bp) {
  int i = blockIdx.x * 256 + threadIdx.x;   // 73728 total
  int c = i & 31, o = (i >> 5) & 127, pp = i >> 12;
  int cg = pp / 9, pos = pp - cg * 9;
  Bp[i] = (short)f2bf(w2[o * 576 + (cg * 32 + c) * 9 + pos]);
}

// ---------------------------------------------------------------------------
// conv2 implicit-GEMM MFMA (round-8 version, reverted): 512 thr = 8 waves, 2M x 4N.
// wave = M 128 px (8 m-frags) x N 32 o (2 n-frags).
// ---------------------------------------------------------------------------
__global__ __launch_bounds__(512) void conv2_mfma(
    const short* __restrict__ yin, const short* __restrict__ Bp,
    const float* __restrict__ b2, unsigned int* __restrict__ A32) {
  __shared__ short tile[324 * 40];
  const int t = threadIdx.x;
  const int blk = blockIdx.x;
  const int tx = blk & 3, ty = (blk >> 2) & 3, b = blk >> 4;
  const int w = t >> 6, lane = t & 63;
  const int wm = w & 1, wn = w >> 1;          // 2M x 4N wave grid
  const int l15 = lane & 15, lg = lane >> 4;

  f32x4 acc[8][2];
#pragma unroll
  for (int m = 0; m < 8; ++m)
#pragma unroll
    for (int n = 0; n < 2; ++n) acc[m][n] = (f32x4){0.f, 0.f, 0.f, 0.f};

  const int ih0 = ty * 16 - 1, iw0 = tx * 16 - 1;

#pragma unroll
  for (int cg = 0; cg < 2; ++cg) {
    __syncthreads();
    for (int i = t; i < 324 * 4; i += 512) {
      int p = i >> 2, q = i & 3;
      int sy = p / 18, sx = p - sy * 18;
      int ih = ih0 + sy, iw = iw0 + sx;
      short8 v = (short8){0, 0, 0, 0, 0, 0, 0, 0};
      if (((unsigned)ih < 64u) && ((unsigned)iw < 64u))
        v = *(const short8*)(yin + ((((size_t)b << 6) + ih) << 12) + ((size_t)iw << 6) + cg * 32 + q * 8);
      *(short8*)&tile[p * 40 + q * 8] = v;
    }
    __syncthreads();

    const int py0 = wm * 8;
#pragma unroll
    for (int pos = 0; pos < 9; ++pos) {
      const int kh = pos / 3, kw = pos % 3;
      short8 bf[2];
#pragma unroll
      for (int n = 0; n < 2; ++n)
        bf[n] = *(const short8*)(Bp + ((((cg * 9 + pos) << 7) + (wn * 2 + n) * 16 + l15) << 5) + (lg << 3));
#pragma unroll
      for (int half = 0; half < 2; ++half) {
        short8 af[4];
#pragma unroll
        for (int m = 0; m < 4; ++m) {
          int sy = py0 + half * 4 + m + kh, sx = l15 + kw;
          af[m] = *(const short8*)&tile[(sy * 18 + sx) * 40 + lg * 8];
        }
#pragma unroll
        for (int n = 0; n < 2; ++n)
#pragma unroll
          for (int m = 0; m < 4; ++m)
            acc[half * 4 + m][n] = __builtin_amdgcn_mfma_f32_16x16x32_bf16(af[m], bf[n], acc[half * 4 + m][n], 0, 0, 0);
      }
    }
  }

  const size_t bbase = ((size_t)b << 16);   // u32 units
#pragma unroll
  for (int n = 0; n < 2; ++n) {
    const int o = (wn * 2 + n) * 16 + l15;
    const float bias = b2[o];
#pragma unroll
    for (int mp = 0; mp < 4; ++mp) {
      const int prow = ty * 8 + wm * 4 + mp;
      float v0 = fmaxf(fmaxf(acc[2 * mp][n][0], acc[2 * mp][n][1]),
                       fmaxf(acc[2 * mp + 1][n][0], acc[2 * mp + 1][n][1]));
      float v1 = fmaxf(fmaxf(acc[2 * mp][n][2], acc[2 * mp][n][3]),
                       fmaxf(acc[2 * mp + 1][n][2], acc[2 * mp + 1][n][3]));
      v0 = fmaxf(v0 + bias, 0.f);
      v1 = fmaxf(v1 + bias, 0.f);
      unsigned pk = (unsigned)f2bf(v0) | ((unsigned)f2bf(v1) << 16);
      A32[bbase + (size_t)o * 512 + prow * 16 + tx * 4 + lg] = pk;
    }
  }
}

// ---------------------------------------------------------------------------
// fc1 MFMA, W streamed DIRECT from global (no LDS round-trip for W):
// grid 512 = kc; block 256 thr = 4 waves; wave = M64 x N64 (wn = wave id).
// K-chunk 256: A[64][256] bf16 staged once in LDS (one barrier), then waves
// free-run 8 k-slices; B-fragments = 2x float4 per lane + cvt_pk (coalesced,
// each W element read exactly once). P[512][64][256] fp32 partials.
// ---------------------------------------------------------------------------
__global__ __launch_bounds__(256) void fc1_mfma(
    const unsigned short* __restrict__ A, const float* __restrict__ W,
    float* __restrict__ P) {
  __shared__ short Al[64][264];
  const int t = threadIdx.x;
  const int kc = blockIdx.x;                  // 0..511
  const int wn = t >> 6, lane = t & 63;
  const int l15 = lane & 15, lg = lane >> 4;

  // stage A: row = t>>2 (0..63), q = t&3 -> 64 k-elems each (8 x short8)
  {
    const int row = t >> 2, q = t & 3;
    const unsigned short* asrc = A + (size_t)row * KFC + kc * 256 + q * 64;
    short8 ar[8];
#pragma unroll
    for (int i = 0; i < 8; ++i) ar[i] = *(const short8*)(asrc + i * 8);
#pragma unroll
    for (int i = 0; i < 8; ++i) *(short8*)&Al[row][q * 64 + i * 8] = ar[i];
  }
  __syncthreads();

  f32x4 acc[4][4];
#pragma unroll
  for (int m = 0; m < 4; ++m)
#pragma unroll
    for (int n = 0; n < 4; ++n) acc[m][n] = (f32x4){0.f, 0.f, 0.f, 0.f};

  const float* wrow[4];
#pragma unroll
  for (int n = 0; n < 4; ++n)
    wrow[n] = W + (size_t)(wn * 64 + n * 16 + l15) * KFC + kc * 256 + lg * 8;

#pragma unroll
  for (int ks = 0; ks < 8; ++ks) {
    short8 bf[4];
#pragma unroll
    for (int n = 0; n < 4; ++n) {
      f32x4 u = *(const f32x4*)(wrow[n] + ks * 32);
      f32x4 v = *(const f32x4*)(wrow[n] + ks * 32 + 4);
      union { short8 s; unsigned u32[4]; } pk;
      pk.u32[0] = pk2bf(u[0], u[1]);
      pk.u32[1] = pk2bf(u[2], u[3]);
      pk.u32[2] = pk2bf(v[0], v[1]);
      pk.u32[3] = pk2bf(v[2], v[3]);
      bf[n] = pk.s;
    }
    short8 af[4];
#pragma unroll
    for (int m = 0; m < 4; ++m)
      af[m] = *(const short8*)&Al[m * 16 + l15][ks * 32 + lg * 8];
#pragma unroll
    for (int n = 0; n < 4; ++n)
#pragma unroll
      for (int m = 0; m < 4; ++m)
        acc[m][n] = __builtin_amdgcn_mfma_f32_16x16x32_bf16(af[m], bf[n], acc[m][n], 0, 0, 0);
  }

  float* dst = P + (size_t)kc * 16384;
#pragma unroll
  for (int m = 0; m < 4; ++m)
#pragma unroll
    for (int n = 0; n < 4; ++n)
#pragma unroll
      for (int j = 0; j < 4; ++j) {
        int brow = m * 16 + lg * 4 + j;
        int o = wn * 64 + n * 16 + l15;
        dst[brow * 256 + o] = acc[m][n][j];
      }
}

// fc1 partial reduce + bias + relu -> Y[64,256]. 256 blocks, coalesced;
// 4 p-groups of 128 partials each, LDS combine.
__global__ __launch_bounds__(256) void fc1_reduce_kernel(
    const float* __restrict__ P, const float* __restrict__ fb1,
    float* __restrict__ Y) {
  __shared__ float red[4][64];
  const int t = threadIdx.x;
  const int iq = t & 63, pg = t >> 6;
  const int gidx = blockIdx.x * 64 + iq;
  const float* p0 = P + (size_t)(pg * 128) * 16384 + gidx;
  float s0 = 0, s1 = 0, s2 = 0, s3 = 0;
  for (int p = 0; p < 128; p += 4) {
    s0 += p0[(size_t)(p + 0) * 16384];
    s1 += p0[(size_t)(p + 1) * 16384];
    s2 += p0[(size_t)(p + 2) * 16384];
    s3 += p0[(size_t)(p + 3) * 16384];
  }
  red[pg][iq] = (s0 + s1) + (s2 + s3);
  __syncthreads();
  if (pg == 0) {
    float tot = (red[0][iq] + red[1][iq]) + (red[2][iq] + red[3][iq]);
    Y[gidx] = fmaxf(tot + fb1[gidx & 255], 0.f);
  }
}

// fc2: out[64,1000] = Y[64,256] @ W2[1000,256]^T + b2
__global__ __launch_bounds__(256) void fc2_kernel(
    const float* __restrict__ Y, const float* __restrict__ W2,
    const float* __restrict__ b2, float* __restrict__ out) {
  int tid = blockIdx.x * 256 + threadIdx.x;
  if (tid >= 64 * NCLS) return;
  int b = tid / NCLS, n = tid - b * NCLS;
  const float4* yv = (const float4*)(Y + b * 256);
  const float4* wv = (const float4*)(W2 + n * 256);
  float acc = 0.f;
#pragma unroll 8
  for (int f = 0; f < 64; ++f) {
    float4 a = yv[f], w = wv[f];
    acc += a.x * w.x + a.y * w.y + a.z * w.z + a.w * w.w;
  }
  out[tid] = acc + b2[n];
}

// ---------------------------------------------------------------------------
extern "C" void kernel_launch(void* const* d_in, const int* in_sizes, int n_in,
                              void* d_out, int out_size, void* d_ws, size_t ws_size,
                              hipStream_t stream) {
  const float* x   = (const float*)d_in[0];
  const float* w1  = (const float*)d_in[1];
  const float* b1  = (const float*)d_in[2];
  const float* w2  = (const float*)d_in[3];
  const float* b2  = (const float*)d_in[4];
  const float* fw1 = (const float*)d_in[5];
  const float* fb1 = (const float*)d_in[6];
  const float* fw2 = (const float*)d_in[7];
  const float* fb2 = (const float*)d_in[8];
  float* out = (float*)d_out;

  unsigned short* Y1 = (unsigned short*)d_ws;              // conv1 out bf16 NHWC [16777216]
  unsigned short* A16 = Y1 + 16777216;                     // conv2 out bf16 [8388608]
  short* Bp = (short*)(A16 + 8388608);                     // conv2 weights bf16 [73728]
  float* P  = (float*)(Bp + 73728);                        // fc1 partials [512*16384]
  float* Yf = P + 8388608;                                 // fc1 out [16384]

  prep_w2<<<288, 256, 0, stream>>>(w2, Bp);
  conv1_kernel<<<2048, 256, 0, stream>>>(x, w1, b1, Y1);
  conv2_mfma<<<1024, 512, 0, stream>>>((const short*)Y1, Bp, b2, (unsigned int*)A16);
  fc1_mfma<<<512, 256, 0, stream>>>(A16, fw1, P);
  fc1_reduce_kernel<<<256, 256, 0, stream>>>(P, fb1, Yf);
  fc2_kernel<<<250, 256, 0, stream>>>(Yf, fw2, fb2, out);
}

// Round 11
// 125.218 us; speedup vs baseline: 1.4167x; 1.2159x over previous
//
#include <hip/hip_runtime.h>
#include <hip/hip_bf16.h>

typedef __attribute__((ext_vector_type(8))) short short8;
typedef __attribute__((ext_vector_type(4))) float f32x4;

#define KFC   131072   // 128*32*32
#define NCLS  1000

__device__ __forceinline__ unsigned short f2bf(float f) {
  union { float f; unsigned u; } v; v.f = f;
  unsigned r = v.u + 0x7FFFu + ((v.u >> 16) & 1u);   // RNE
  return (unsigned short)(r >> 16);
}

__device__ __forceinline__ unsigned pk2bf(float a, float b) {
  __hip_bfloat162 h = __float22bfloat162_rn(float2{a, b});
  union { __hip_bfloat162 h; unsigned u; } c; c.h = h;
  return c.u;
}

// ---------------------------------------------------------------------------
// prep_w1: w1[64][27] fp32 -> Bp1[64 o][32 k] bf16, k = ci*9 + kh*3 + kw, pad 0
// ---------------------------------------------------------------------------
__global__ __launch_bounds__(256) void prep_w1(
    const float* __restrict__ w1, short* __restrict__ Bp1) {
  int i = blockIdx.x * 256 + threadIdx.x;   // 2048
  int o = i >> 5, k = i & 31;
  Bp1[i] = (k < 27) ? (short)f2bf(w1[o * 27 + k]) : (short)0;
}

// ---------------------------------------------------------------------------
// conv1 via MFMA: x[64,3,128,128] fp32 -> y[64,64,64,64] bf16 NHWC.
// Implicit GEMM, K=27 padded to one 16x16x32 k-slice.
// grid 4096 = b x 8x8 tiles of 16x16 conv px; block 256 = 4 waves x 4 conv rows.
// LDS: bf16 halo [3][18][20] + zero slot. A-frag = 8 ds_read_u16 per lane.
// ---------------------------------------------------------------------------
__global__ __launch_bounds__(256) void conv1_mfma(
    const float* __restrict__ x, const short* __restrict__ Bp1,
    const float* __restrict__ b1, unsigned short* __restrict__ y) {
  __shared__ unsigned short tile[1152];     // [3][18][20] = 1080, rest zeroed
  const int t = threadIdx.x;
  const int blk = blockIdx.x;               // b*64 + ty*8 + tx
  const int tx = blk & 7, ty = (blk >> 3) & 7, b = blk >> 6;
  const int w = t >> 6, lane = t & 63;
  const int l15 = lane & 15, lg = lane >> 4;

  // stage halo fp32 -> bf16 (tc>=18 pad and out-of-image -> 0; 1080.. zeroed)
  const int ih0 = ty * 16 - 1, iw0 = tx * 16 - 1;
  for (int i = t; i < 1152; i += 256) {
    unsigned short v = 0;
    if (i < 1080) {
      int ci = i / 360, rem = i - ci * 360;
      int tr = rem / 20, tc = rem - tr * 20;
      int ih = ih0 + tr, iw = iw0 + tc;
      if (tc < 18 && (unsigned)ih < 128u && (unsigned)iw < 128u)
        v = f2bf(x[(b * 3 + ci) * 16384 + (ih << 7) + iw]);
    }
    tile[i] = v;
  }

  // B-fragments (L2-resident, hoisted) and per-lane A gather offsets
  short8 bf[4];
#pragma unroll
  for (int n = 0; n < 4; ++n)
    bf[n] = *(const short8*)(Bp1 + ((n * 16 + l15) << 5) + (lg << 3));

  int soff[8];
#pragma unroll
  for (int j = 0; j < 8; ++j) {
    int k = lg * 8 + j;
    if (k < 27) {
      int ci = k / 9, rem = k - ci * 9;
      int r = rem / 3, s = rem - r * 3;
      soff[j] = ci * 360 + r * 20 + s + l15 + w * 80;   // + rr_off*20 via w*80 + m*20
    } else {
      soff[j] = 1080;                                   // zero slot (1080+60 < 1152)
    }
  }
  __syncthreads();

  f32x4 acc[4][4];
#pragma unroll
  for (int m = 0; m < 4; ++m)
#pragma unroll
    for (int n = 0; n < 4; ++n) acc[m][n] = (f32x4){0.f, 0.f, 0.f, 0.f};

#pragma unroll
  for (int m = 0; m < 4; ++m) {
    union { short8 s; unsigned short u[8]; } af;
#pragma unroll
    for (int j = 0; j < 8; ++j) af.u[j] = tile[soff[j] + m * 20];
#pragma unroll
    for (int n = 0; n < 4; ++n)
      acc[m][n] = __builtin_amdgcn_mfma_f32_16x16x32_bf16(af.s, bf[n], acc[m][n], 0, 0, 0);
  }

  // epilogue: D-row(lg*4+reg) = pixel col, D-col(l15) = o; m-frag = conv row w*4+m
  // pool: m-frag pairs (2q,2q+1) x reg pairs (0,1),(2,3)
#pragma unroll
  for (int n = 0; n < 4; ++n) {
    const int o = n * 16 + l15;
    const float bias = b1[o];
#pragma unroll
    for (int q = 0; q < 2; ++q) {
      const int pr = ty * 8 + w * 2 + q;
      float v0 = fmaxf(fmaxf(acc[2 * q][n][0], acc[2 * q][n][1]),
                       fmaxf(acc[2 * q + 1][n][0], acc[2 * q + 1][n][1]));
      float v1 = fmaxf(fmaxf(acc[2 * q][n][2], acc[2 * q][n][3]),
                       fmaxf(acc[2 * q + 1][n][2], acc[2 * q + 1][n][3]));
      v0 = fmaxf(v0 + bias, 0.f);
      v1 = fmaxf(v1 + bias, 0.f);
      const int pc = tx * 8 + lg * 2;
      unsigned short* dst = y + ((((size_t)b << 6) + pr) << 12) + ((size_t)pc << 6) + o;
      dst[0]  = f2bf(v0);
      dst[64] = f2bf(v1);
    }
  }
}

// ---------------------------------------------------------------------------
// weight reorder for conv2: Bprep[((cg*9+pos)*128 + o)*32 + c] = bf16(w2[o][(cg*32+c)*9 + pos])
// ---------------------------------------------------------------------------
__global__ __launch_bounds__(256) void prep_w2(
    const float* __restrict__ w2, short* __restrict__ Bp) {
  int i = blockIdx.x * 256 + threadIdx.x;   // 73728 total
  int c = i & 31, o = (i >> 5) & 127, pp = i >> 12;
  int cg = pp / 9, pos = pp - cg * 9;
  Bp[i] = (short)f2bf(w2[o * 576 + (cg * 32 + c) * 9 + pos]);
}

// ---------------------------------------------------------------------------
// conv2 implicit-GEMM MFMA: 512 thr = 8 waves, 2M x 4N.
// wave = M 128 px (8 m-frags) x N 32 o (2 n-frags).
// ---------------------------------------------------------------------------
__global__ __launch_bounds__(512) void conv2_mfma(
    const short* __restrict__ yin, const short* __restrict__ Bp,
    const float* __restrict__ b2, unsigned int* __restrict__ A32) {
  __shared__ short tile[324 * 40];
  const int t = threadIdx.x;
  const int blk = blockIdx.x;
  const int tx = blk & 3, ty = (blk >> 2) & 3, b = blk >> 4;
  const int w = t >> 6, lane = t & 63;
  const int wm = w & 1, wn = w >> 1;          // 2M x 4N wave grid
  const int l15 = lane & 15, lg = lane >> 4;

  f32x4 acc[8][2];
#pragma unroll
  for (int m = 0; m < 8; ++m)
#pragma unroll
    for (int n = 0; n < 2; ++n) acc[m][n] = (f32x4){0.f, 0.f, 0.f, 0.f};

  const int ih0 = ty * 16 - 1, iw0 = tx * 16 - 1;

#pragma unroll
  for (int cg = 0; cg < 2; ++cg) {
    __syncthreads();
    for (int i = t; i < 324 * 4; i += 512) {
      int p = i >> 2, q = i & 3;
      int sy = p / 18, sx = p - sy * 18;
      int ih = ih0 + sy, iw = iw0 + sx;
      short8 v = (short8){0, 0, 0, 0, 0, 0, 0, 0};
      if (((unsigned)ih < 64u) && ((unsigned)iw < 64u))
        v = *(const short8*)(yin + ((((size_t)b << 6) + ih) << 12) + ((size_t)iw << 6) + cg * 32 + q * 8);
      *(short8*)&tile[p * 40 + q * 8] = v;
    }
    __syncthreads();

    const int py0 = wm * 8;
#pragma unroll
    for (int pos = 0; pos < 9; ++pos) {
      const int kh = pos / 3, kw = pos % 3;
      short8 bf[2];
#pragma unroll
      for (int n = 0; n < 2; ++n)
        bf[n] = *(const short8*)(Bp + ((((cg * 9 + pos) << 7) + (wn * 2 + n) * 16 + l15) << 5) + (lg << 3));
#pragma unroll
      for (int half = 0; half < 2; ++half) {
        short8 af[4];
#pragma unroll
        for (int m = 0; m < 4; ++m) {
          int sy = py0 + half * 4 + m + kh, sx = l15 + kw;
          af[m] = *(const short8*)&tile[(sy * 18 + sx) * 40 + lg * 8];
        }
#pragma unroll
        for (int n = 0; n < 2; ++n)
#pragma unroll
          for (int m = 0; m < 4; ++m)
            acc[half * 4 + m][n] = __builtin_amdgcn_mfma_f32_16x16x32_bf16(af[m], bf[n], acc[half * 4 + m][n], 0, 0, 0);
      }
    }
  }

  const size_t bbase = ((size_t)b << 16);   // u32 units
#pragma unroll
  for (int n = 0; n < 2; ++n) {
    const int o = (wn * 2 + n) * 16 + l15;
    const float bias = b2[o];
#pragma unroll
    for (int mp = 0; mp < 4; ++mp) {
      const int prow = ty * 8 + wm * 4 + mp;
      float v0 = fmaxf(fmaxf(acc[2 * mp][n][0], acc[2 * mp][n][1]),
                       fmaxf(acc[2 * mp + 1][n][0], acc[2 * mp + 1][n][1]));
      float v1 = fmaxf(fmaxf(acc[2 * mp][n][2], acc[2 * mp][n][3]),
                       fmaxf(acc[2 * mp + 1][n][2], acc[2 * mp + 1][n][3]));
      v0 = fmaxf(v0 + bias, 0.f);
      v1 = fmaxf(v1 + bias, 0.f);
      unsigned pk = (unsigned)f2bf(v0) | ((unsigned)f2bf(v1) << 16);
      A32[bbase + (size_t)o * 512 + prow * 16 + tx * 4 + lg] = pk;
    }
  }
}

// ---------------------------------------------------------------------------
// fc1 MFMA, W streamed direct from global (no LDS round-trip for W):
// grid 512 = kc; block 256 thr = 4 waves; wave = M64 x N64.
// ---------------------------------------------------------------------------
__global__ __launch_bounds__(256) void fc1_mfma(
    const unsigned short* __restrict__ A, const float* __restrict__ W,
    float* __restrict__ P) {
  __shared__ short Al[64][264];
  const int t = threadIdx.x;
  const int kc = blockIdx.x;                  // 0..511
  const int wn = t >> 6, lane = t & 63;
  const int l15 = lane & 15, lg = lane >> 4;

  {
    const int row = t >> 2, q = t & 3;
    const unsigned short* asrc = A + (size_t)row * KFC + kc * 256 + q * 64;
    short8 ar[8];
#pragma unroll
    for (int i = 0; i < 8; ++i) ar[i] = *(const short8*)(asrc + i * 8);
#pragma unroll
    for (int i = 0; i < 8; ++i) *(short8*)&Al[row][q * 64 + i * 8] = ar[i];
  }
  __syncthreads();

  f32x4 acc[4][4];
#pragma unroll
  for (int m = 0; m < 4; ++m)
#pragma unroll
    for (int n = 0; n < 4; ++n) acc[m][n] = (f32x4){0.f, 0.f, 0.f, 0.f};

  const float* wrow[4];
#pragma unroll
  for (int n = 0; n < 4; ++n)
    wrow[n] = W + (size_t)(wn * 64 + n * 16 + l15) * KFC + kc * 256 + lg * 8;

#pragma unroll
  for (int ks = 0; ks < 8; ++ks) {
    short8 bf[4];
#pragma unroll
    for (int n = 0; n < 4; ++n) {
      f32x4 u = *(const f32x4*)(wrow[n] + ks * 32);
      f32x4 v = *(const f32x4*)(wrow[n] + ks * 32 + 4);
      union { short8 s; unsigned u32[4]; } pk;
      pk.u32[0] = pk2bf(u[0], u[1]);
      pk.u32[1] = pk2bf(u[2], u[3]);
      pk.u32[2] = pk2bf(v[0], v[1]);
      pk.u32[3] = pk2bf(v[2], v[3]);
      bf[n] = pk.s;
    }
    short8 af[4];
#pragma unroll
    for (int m = 0; m < 4; ++m)
      af[m] = *(const short8*)&Al[m * 16 + l15][ks * 32 + lg * 8];
#pragma unroll
    for (int n = 0; n < 4; ++n)
#pragma unroll
      for (int m = 0; m < 4; ++m)
        acc[m][n] = __builtin_amdgcn_mfma_f32_16x16x32_bf16(af[m], bf[n], acc[m][n], 0, 0, 0);
  }

  float* dst = P + (size_t)kc * 16384;
#pragma unroll
  for (int m = 0; m < 4; ++m)
#pragma unroll
    for (int n = 0; n < 4; ++n)
#pragma unroll
      for (int j = 0; j < 4; ++j) {
        int brow = m * 16 + lg * 4 + j;
        int o = wn * 64 + n * 16 + l15;
        dst[brow * 256 + o] = acc[m][n][j];
      }
}

// fc1 partial reduce + bias + relu -> Y[64,256]. 256 blocks, coalesced.
__global__ __launch_bounds__(256) void fc1_reduce_kernel(
    const float* __restrict__ P, const float* __restrict__ fb1,
    float* __restrict__ Y) {
  __shared__ float red[4][64];
  const int t = threadIdx.x;
  const int iq = t & 63, pg = t >> 6;
  const int gidx = blockIdx.x * 64 + iq;
  const float* p0 = P + (size_t)(pg * 128) * 16384 + gidx;
  float s0 = 0, s1 = 0, s2 = 0, s3 = 0;
  for (int p = 0; p < 128; p += 4) {
    s0 += p0[(size_t)(p + 0) * 16384];
    s1 += p0[(size_t)(p + 1) * 16384];
    s2 += p0[(size_t)(p + 2) * 16384];
    s3 += p0[(size_t)(p + 3) * 16384];
  }
  red[pg][iq] = (s0 + s1) + (s2 + s3);
  __syncthreads();
  if (pg == 0) {
    float tot = (red[0][iq] + red[1][iq]) + (red[2][iq] + red[3][iq]);
    Y[gidx] = fmaxf(tot + fb1[gidx & 255], 0.f);
  }
}

// fc2: out[64,1000] = Y[64,256] @ W2[1000,256]^T + b2
__global__ __launch_bounds__(256) void fc2_kernel(
    const float* __restrict__ Y, const float* __restrict__ W2,
    const float* __restrict__ b2, float* __restrict__ out) {
  int tid = blockIdx.x * 256 + threadIdx.x;
  if (tid >= 64 * NCLS) return;
  int b = tid / NCLS, n = tid - b * NCLS;
  const float4* yv = (const float4*)(Y + b * 256);
  const float4* wv = (const float4*)(W2 + n * 256);
  float acc = 0.f;
#pragma unroll 8
  for (int f = 0; f < 64; ++f) {
    float4 a = yv[f], w = wv[f];
    acc += a.x * w.x + a.y * w.y + a.z * w.z + a.w * w.w;
  }
  out[tid] = acc + b2[n];
}

// ---------------------------------------------------------------------------
extern "C" void kernel_launch(void* const* d_in, const int* in_sizes, int n_in,
                              void* d_out, int out_size, void* d_ws, size_t ws_size,
                              hipStream_t stream) {
  const float* x   = (const float*)d_in[0];
  const float* w1  = (const float*)d_in[1];
  const float* b1  = (const float*)d_in[2];
  const float* w2  = (const float*)d_in[3];
  const float* b2  = (const float*)d_in[4];
  const float* fw1 = (const float*)d_in[5];
  const float* fb1 = (const float*)d_in[6];
  const float* fw2 = (const float*)d_in[7];
  const float* fb2 = (const float*)d_in[8];
  float* out = (float*)d_out;

  unsigned short* Y1 = (unsigned short*)d_ws;              // conv1 out bf16 NHWC [16777216]
  unsigned short* A16 = Y1 + 16777216;                     // conv2 out bf16 [8388608]
  short* Bp = (short*)(A16 + 8388608);                     // conv2 weights bf16 [73728]
  short* Bp1 = Bp + 73728;                                 // conv1 weights bf16 [2048]
  float* P  = (float*)(Bp1 + 2048);                        // fc1 partials [512*16384]
  float* Yf = P + 8388608;                                 // fc1 out [16384]

  prep_w2<<<288, 256, 0, stream>>>(w2, Bp);
  prep_w1<<<8, 256, 0, stream>>>(w1, Bp1);
  conv1_mfma<<<4096, 256, 0, stream>>>(x, Bp1, b1, Y1);
  conv2_mfma<<<1024, 512, 0, stream>>>((const short*)Y1, Bp, b2, (unsigned int*)A16);
  fc1_mfma<<<512, 256, 0, stream>>>(A16, fw1, P);
  fc1_reduce_kernel<<<256, 256, 0, stream>>>(P, fb1, Yf);
  fc2_kernel<<<250, 256, 0, stream>>>(Yf, fw2, fb2, out);
}

// Round 12
// 124.987 us; speedup vs baseline: 1.4193x; 1.0018x over previous
//
#include <hip/hip_runtime.h>
#include <hip/hip_bf16.h>

typedef __attribute__((ext_vector_type(8))) short short8;
typedef __attribute__((ext_vector_type(4))) float f32x4;

#define KFC   131072   // 128*32*32
#define NCLS  1000

__device__ __forceinline__ unsigned short f2bf(float f) {
  union { float f; unsigned u; } v; v.f = f;
  unsigned r = v.u + 0x7FFFu + ((v.u >> 16) & 1u);   // RNE
  return (unsigned short)(r >> 16);
}

__device__ __forceinline__ unsigned pk2bf(float a, float b) {
  __hip_bfloat162 h = __float22bfloat162_rn(float2{a, b});
  union { __hip_bfloat162 h; unsigned u; } c; c.h = h;
  return c.u;
}

// ---------------------------------------------------------------------------
// prep_w1: w1[64][27] fp32 -> Bp1[64 o][32 k] bf16, k = ci*9 + kh*3 + kw, pad 0
// ---------------------------------------------------------------------------
__global__ __launch_bounds__(256) void prep_w1(
    const float* __restrict__ w1, short* __restrict__ Bp1) {
  int i = blockIdx.x * 256 + threadIdx.x;   // 2048
  int o = i >> 5, k = i & 31;
  Bp1[i] = (k < 27) ? (short)f2bf(w1[o * 27 + k]) : (short)0;
}

// ---------------------------------------------------------------------------
// conv1 via MFMA: x[64,3,128,128] fp32 -> y[64,64,64,64] bf16 NHWC.
// Implicit GEMM, K=27 padded to one 16x16x32 k-slice.
// ---------------------------------------------------------------------------
__global__ __launch_bounds__(256) void conv1_mfma(
    const float* __restrict__ x, const short* __restrict__ Bp1,
    const float* __restrict__ b1, unsigned short* __restrict__ y) {
  __shared__ unsigned short tile[1152];     // [3][18][20] = 1080, rest zeroed
  const int t = threadIdx.x;
  const int blk = blockIdx.x;               // b*64 + ty*8 + tx
  const int tx = blk & 7, ty = (blk >> 3) & 7, b = blk >> 6;
  const int w = t >> 6, lane = t & 63;
  const int l15 = lane & 15, lg = lane >> 4;

  const int ih0 = ty * 16 - 1, iw0 = tx * 16 - 1;
  for (int i = t; i < 1152; i += 256) {
    unsigned short v = 0;
    if (i < 1080) {
      int ci = i / 360, rem = i - ci * 360;
      int tr = rem / 20, tc = rem - tr * 20;
      int ih = ih0 + tr, iw = iw0 + tc;
      if (tc < 18 && (unsigned)ih < 128u && (unsigned)iw < 128u)
        v = f2bf(x[(b * 3 + ci) * 16384 + (ih << 7) + iw]);
    }
    tile[i] = v;
  }

  short8 bf[4];
#pragma unroll
  for (int n = 0; n < 4; ++n)
    bf[n] = *(const short8*)(Bp1 + ((n * 16 + l15) << 5) + (lg << 3));

  int soff[8];
#pragma unroll
  for (int j = 0; j < 8; ++j) {
    int k = lg * 8 + j;
    if (k < 27) {
      int ci = k / 9, rem = k - ci * 9;
      int r = rem / 3, s = rem - r * 3;
      soff[j] = ci * 360 + r * 20 + s + l15 + w * 80;
    } else {
      soff[j] = 1080;
    }
  }
  __syncthreads();

  f32x4 acc[4][4];
#pragma unroll
  for (int m = 0; m < 4; ++m)
#pragma unroll
    for (int n = 0; n < 4; ++n) acc[m][n] = (f32x4){0.f, 0.f, 0.f, 0.f};

#pragma unroll
  for (int m = 0; m < 4; ++m) {
    union { short8 s; unsigned short u[8]; } af;
#pragma unroll
    for (int j = 0; j < 8; ++j) af.u[j] = tile[soff[j] + m * 20];
#pragma unroll
    for (int n = 0; n < 4; ++n)
      acc[m][n] = __builtin_amdgcn_mfma_f32_16x16x32_bf16(af.s, bf[n], acc[m][n], 0, 0, 0);
  }

#pragma unroll
  for (int n = 0; n < 4; ++n) {
    const int o = n * 16 + l15;
    const float bias = b1[o];
#pragma unroll
    for (int q = 0; q < 2; ++q) {
      const int pr = ty * 8 + w * 2 + q;
      float v0 = fmaxf(fmaxf(acc[2 * q][n][0], acc[2 * q][n][1]),
                       fmaxf(acc[2 * q + 1][n][0], acc[2 * q + 1][n][1]));
      float v1 = fmaxf(fmaxf(acc[2 * q][n][2], acc[2 * q][n][3]),
                       fmaxf(acc[2 * q + 1][n][2], acc[2 * q + 1][n][3]));
      v0 = fmaxf(v0 + bias, 0.f);
      v1 = fmaxf(v1 + bias, 0.f);
      const int pc = tx * 8 + lg * 2;
      unsigned short* dst = y + ((((size_t)b << 6) + pr) << 12) + ((size_t)pc << 6) + o;
      dst[0]  = f2bf(v0);
      dst[64] = f2bf(v1);
    }
  }
}

// ---------------------------------------------------------------------------
// weight reorder for conv2: Bprep[((cg*9+pos)*128 + o)*32 + c] = bf16(w2[o][(cg*32+c)*9 + pos])
// ---------------------------------------------------------------------------
__global__ __launch_bounds__(256) void prep_w2(
    const float* __restrict__ w2, short* __restrict__ Bp) {
  int i = blockIdx.x * 256 + threadIdx.x;   // 73728 total
  int c = i & 31, o = (i >> 5) & 127, pp = i >> 12;
  int cg = pp / 9, pos = pp - cg * 9;
  Bp[i] = (short)f2bf(w2[o * 576 + (cg * 32 + c) * 9 + pos]);
}

// ---------------------------------------------------------------------------
// conv2 implicit-GEMM MFMA: 512 thr = 8 waves, 2M x 4N (round-8 layout), with
// kw-outer row-caching: per (cg,kw) preload bf[3][2]; per half cache 6 rows;
// af[m,kh] = rc[m+kh]. af ds_reads 144->72/wave; bf unchanged 36/wave.
// ---------------------------------------------------------------------------
__global__ __launch_bounds__(512) void conv2_mfma(
    const short* __restrict__ yin, const short* __restrict__ Bp,
    const float* __restrict__ b2, unsigned int* __restrict__ A32) {
  __shared__ short tile[324 * 40];
  const int t = threadIdx.x;
  const int blk = blockIdx.x;
  const int tx = blk & 3, ty = (blk >> 2) & 3, b = blk >> 4;
  const int w = t >> 6, lane = t & 63;
  const int wm = w & 1, wn = w >> 1;          // 2M x 4N wave grid
  const int l15 = lane & 15, lg = lane >> 4;

  f32x4 acc[8][2];
#pragma unroll
  for (int m = 0; m < 8; ++m)
#pragma unroll
    for (int n = 0; n < 2; ++n) acc[m][n] = (f32x4){0.f, 0.f, 0.f, 0.f};

  const int ih0 = ty * 16 - 1, iw0 = tx * 16 - 1;

#pragma unroll
  for (int cg = 0; cg < 2; ++cg) {
    __syncthreads();
    for (int i = t; i < 324 * 4; i += 512) {
      int p = i >> 2, q = i & 3;
      int sy = p / 18, sx = p - sy * 18;
      int ih = ih0 + sy, iw = iw0 + sx;
      short8 v = (short8){0, 0, 0, 0, 0, 0, 0, 0};
      if (((unsigned)ih < 64u) && ((unsigned)iw < 64u))
        v = *(const short8*)(yin + ((((size_t)b << 6) + ih) << 12) + ((size_t)iw << 6) + cg * 32 + q * 8);
      *(short8*)&tile[p * 40 + q * 8] = v;
    }
    __syncthreads();

    const int py0 = wm * 8;
#pragma unroll
    for (int kw = 0; kw < 3; ++kw) {
      short8 bf[3][2];
#pragma unroll
      for (int kh = 0; kh < 3; ++kh)
#pragma unroll
        for (int n = 0; n < 2; ++n)
          bf[kh][n] = *(const short8*)(Bp + ((((cg * 9 + kh * 3 + kw) << 7) + (wn * 2 + n) * 16 + l15) << 5) + (lg << 3));
#pragma unroll
      for (int half = 0; half < 2; ++half) {
        short8 rc[6];
#pragma unroll
        for (int r = 0; r < 6; ++r) {
          int sy = py0 + half * 4 + r, sx = l15 + kw;
          rc[r] = *(const short8*)&tile[(sy * 18 + sx) * 40 + lg * 8];
        }
#pragma unroll
        for (int kh = 0; kh < 3; ++kh)
#pragma unroll
          for (int n = 0; n < 2; ++n)
#pragma unroll
            for (int m = 0; m < 4; ++m)
              acc[half * 4 + m][n] = __builtin_amdgcn_mfma_f32_16x16x32_bf16(rc[m + kh], bf[kh][n], acc[half * 4 + m][n], 0, 0, 0);
      }
    }
  }

  const size_t bbase = ((size_t)b << 16);   // u32 units
#pragma unroll
  for (int n = 0; n < 2; ++n) {
    const int o = (wn * 2 + n) * 16 + l15;
    const float bias = b2[o];
#pragma unroll
    for (int mp = 0; mp < 4; ++mp) {
      const int prow = ty * 8 + wm * 4 + mp;
      float v0 = fmaxf(fmaxf(acc[2 * mp][n][0], acc[2 * mp][n][1]),
                       fmaxf(acc[2 * mp + 1][n][0], acc[2 * mp + 1][n][1]));
      float v1 = fmaxf(fmaxf(acc[2 * mp][n][2], acc[2 * mp][n][3]),
                       fmaxf(acc[2 * mp + 1][n][2], acc[2 * mp + 1][n][3]));
      v0 = fmaxf(v0 + bias, 0.f);
      v1 = fmaxf(v1 + bias, 0.f);
      unsigned pk = (unsigned)f2bf(v0) | ((unsigned)f2bf(v1) << 16);
      A32[bbase + (size_t)o * 512 + prow * 16 + tx * 4 + lg] = pk;
    }
  }
}

// ---------------------------------------------------------------------------
// fc1 MFMA, W streamed direct from global (no LDS round-trip for W):
// grid 512 = kc; block 256 thr = 4 waves; wave = M64 x N64.
// ---------------------------------------------------------------------------
__global__ __launch_bounds__(256) void fc1_mfma(
    const unsigned short* __restrict__ A, const float* __restrict__ W,
    float* __restrict__ P) {
  __shared__ short Al[64][264];
  const int t = threadIdx.x;
  const int kc = blockIdx.x;                  // 0..511
  const int wn = t >> 6, lane = t & 63;
  const int l15 = lane & 15, lg = lane >> 4;

  {
    const int row = t >> 2, q = t & 3;
    const unsigned short* asrc = A + (size_t)row * KFC + kc * 256 + q * 64;
    short8 ar[8];
#pragma unroll
    for (int i = 0; i < 8; ++i) ar[i] = *(const short8*)(asrc + i * 8);
#pragma unroll
    for (int i = 0; i < 8; ++i) *(short8*)&Al[row][q * 64 + i * 8] = ar[i];
  }
  __syncthreads();

  f32x4 acc[4][4];
#pragma unroll
  for (int m = 0; m < 4; ++m)
#pragma unroll
    for (int n = 0; n < 4; ++n) acc[m][n] = (f32x4){0.f, 0.f, 0.f, 0.f};

  const float* wrow[4];
#pragma unroll
  for (int n = 0; n < 4; ++n)
    wrow[n] = W + (size_t)(wn * 64 + n * 16 + l15) * KFC + kc * 256 + lg * 8;

#pragma unroll
  for (int ks = 0; ks < 8; ++ks) {
    short8 bf[4];
#pragma unroll
    for (int n = 0; n < 4; ++n) {
      f32x4 u = *(const f32x4*)(wrow[n] + ks * 32);
      f32x4 v = *(const f32x4*)(wrow[n] + ks * 32 + 4);
      union { short8 s; unsigned u32[4]; } pk;
      pk.u32[0] = pk2bf(u[0], u[1]);
      pk.u32[1] = pk2bf(u[2], u[3]);
      pk.u32[2] = pk2bf(v[0], v[1]);
      pk.u32[3] = pk2bf(v[2], v[3]);
      bf[n] = pk.s;
    }
    short8 af[4];
#pragma unroll
    for (int m = 0; m < 4; ++m)
      af[m] = *(const short8*)&Al[m * 16 + l15][ks * 32 + lg * 8];
#pragma unroll
    for (int n = 0; n < 4; ++n)
#pragma unroll
      for (int m = 0; m < 4; ++m)
        acc[m][n] = __builtin_amdgcn_mfma_f32_16x16x32_bf16(af[m], bf[n], acc[m][n], 0, 0, 0);
  }

  float* dst = P + (size_t)kc * 16384;
#pragma unroll
  for (int m = 0; m < 4; ++m)
#pragma unroll
    for (int n = 0; n < 4; ++n)
#pragma unroll
      for (int j = 0; j < 4; ++j) {
        int brow = m * 16 + lg * 4 + j;
        int o = wn * 64 + n * 16 + l15;
        dst[brow * 256 + o] = acc[m][n][j];
      }
}

// fc1 partial reduce + bias + relu -> Y[64,256]. 256 blocks, coalesced.
__global__ __launch_bounds__(256) void fc1_reduce_kernel(
    const float* __restrict__ P, const float* __restrict__ fb1,
    float* __restrict__ Y) {
  __shared__ float red[4][64];
  const int t = threadIdx.x;
  const int iq = t & 63, pg = t >> 6;
  const int gidx = blockIdx.x * 64 + iq;
  const float* p0 = P + (size_t)(pg * 128) * 16384 + gidx;
  float s0 = 0, s1 = 0, s2 = 0, s3 = 0;
  for (int p = 0; p < 128; p += 4) {
    s0 += p0[(size_t)(p + 0) * 16384];
    s1 += p0[(size_t)(p + 1) * 16384];
    s2 += p0[(size_t)(p + 2) * 16384];
    s3 += p0[(size_t)(p + 3) * 16384];
  }
  red[pg][iq] = (s0 + s1) + (s2 + s3);
  __syncthreads();
  if (pg == 0) {
    float tot = (red[0][iq] + red[1][iq]) + (red[2][iq] + red[3][iq]);
    Y[gidx] = fmaxf(tot + fb1[gidx & 255], 0.f);
  }
}

// fc2: out[64,1000] = Y[64,256] @ W2[1000,256]^T + b2
__global__ __launch_bounds__(256) void fc2_kernel(
    const float* __restrict__ Y, const float* __restrict__ W2,
    const float* __restrict__ b2, float* __restrict__ out) {
  int tid = blockIdx.x * 256 + threadIdx.x;
  if (tid >= 64 * NCLS) return;
  int b = tid / NCLS, n = tid - b * NCLS;
  const float4* yv = (const float4*)(Y + b * 256);
  const float4* wv = (const float4*)(W2 + n * 256);
  float acc = 0.f;
#pragma unroll 8
  for (int f = 0; f < 64; ++f) {
    float4 a = yv[f], w = wv[f];
    acc += a.x * w.x + a.y * w.y + a.z * w.z + a.w * w.w;
  }
  out[tid] = acc + b2[n];
}

// ---------------------------------------------------------------------------
extern "C" void kernel_launch(void* const* d_in, const int* in_sizes, int n_in,
                              void* d_out, int out_size, void* d_ws, size_t ws_size,
                              hipStream_t stream) {
  const float* x   = (const float*)d_in[0];
  const float* w1  = (const float*)d_in[1];
  const float* b1  = (const float*)d_in[2];
  const float* w2  = (const float*)d_in[3];
  const float* b2  = (const float*)d_in[4];
  const float* fw1 = (const float*)d_in[5];
  const float* fb1 = (const float*)d_in[6];
  const float* fw2 = (const float*)d_in[7];
  const float* fb2 = (const float*)d_in[8];
  float* out = (float*)d_out;

  unsigned short* Y1 = (unsigned short*)d_ws;              // conv1 out bf16 NHWC [16777216]
  unsigned short* A16 = Y1 + 16777216;                     // conv2 out bf16 [8388608]
  short* Bp = (short*)(A16 + 8388608);                     // conv2 weights bf16 [73728]
  short* Bp1 = Bp + 73728;                                 // conv1 weights bf16 [2048]
  float* P  = (float*)(Bp1 + 2048);                        // fc1 partials [512*16384]
  float* Yf = P + 8388608;                                 // fc1 out [16384]

  prep_w2<<<288, 256, 0, stream>>>(w2, Bp);
  prep_w1<<<8, 256, 0, stream>>>(w1, Bp1);
  conv1_mfma<<<4096, 256, 0, stream>>>(x, Bp1, b1, Y1);
  conv2_mfma<<<1024, 512, 0, stream>>>((const short*)Y1, Bp, b2, (unsigned int*)A16);
  fc1_mfma<<<512, 256, 0, stream>>>(A16, fw1, P);
  fc1_reduce_kernel<<<256, 256, 0, stream>>>(P, fb1, Yf);
  fc2_kernel<<<250, 256, 0, stream>>>(Yf, fw2, fb2, out);
}

// Round 13
// 120.104 us; speedup vs baseline: 1.4770x; 1.0407x over previous
//
#include <hip/hip_runtime.h>
#include <hip/hip_bf16.h>

typedef __attribute__((ext_vector_type(8))) short short8;
typedef __attribute__((ext_vector_type(4))) float f32x4;

#define KFC   131072   // 128*32*32
#define NCLS  1000

__device__ __forceinline__ unsigned short f2bf(float f) {
  union { float f; unsigned u; } v; v.f = f;
  unsigned r = v.u + 0x7FFFu + ((v.u >> 16) & 1u);   // RNE
  return (unsigned short)(r >> 16);
}

__device__ __forceinline__ unsigned pk2bf(float a, float b) {
  __hip_bfloat162 h = __float22bfloat162_rn(float2{a, b});
  union { __hip_bfloat162 h; unsigned u; } c; c.h = h;
  return c.u;
}

// ---------------------------------------------------------------------------
// prep_w1: w1[64][27] fp32 -> Bp1[64 o][32 k] bf16, k = ci*9 + kh*3 + kw, pad 0
// ---------------------------------------------------------------------------
__global__ __launch_bounds__(256) void prep_w1(
    const float* __restrict__ w1, short* __restrict__ Bp1) {
  int i = blockIdx.x * 256 + threadIdx.x;   // 2048
  int o = i >> 5, k = i & 31;
  Bp1[i] = (k < 27) ? (short)f2bf(w1[o * 27 + k]) : (short)0;
}

// ---------------------------------------------------------------------------
// conv1 via MFMA: x[64,3,128,128] fp32 -> y[64,64,64,64] bf16 NHWC.
// ---------------------------------------------------------------------------
__global__ __launch_bounds__(256) void conv1_mfma(
    const float* __restrict__ x, const short* __restrict__ Bp1,
    const float* __restrict__ b1, unsigned short* __restrict__ y) {
  __shared__ unsigned short tile[1152];     // [3][18][20] = 1080, rest zeroed
  const int t = threadIdx.x;
  const int blk = blockIdx.x;               // b*64 + ty*8 + tx
  const int tx = blk & 7, ty = (blk >> 3) & 7, b = blk >> 6;
  const int w = t >> 6, lane = t & 63;
  const int l15 = lane & 15, lg = lane >> 4;

  const int ih0 = ty * 16 - 1, iw0 = tx * 16 - 1;
  for (int i = t; i < 1152; i += 256) {
    unsigned short v = 0;
    if (i < 1080) {
      int ci = i / 360, rem = i - ci * 360;
      int tr = rem / 20, tc = rem - tr * 20;
      int ih = ih0 + tr, iw = iw0 + tc;
      if (tc < 18 && (unsigned)ih < 128u && (unsigned)iw < 128u)
        v = f2bf(x[(b * 3 + ci) * 16384 + (ih << 7) + iw]);
    }
    tile[i] = v;
  }

  short8 bf[4];
#pragma unroll
  for (int n = 0; n < 4; ++n)
    bf[n] = *(const short8*)(Bp1 + ((n * 16 + l15) << 5) + (lg << 3));

  int soff[8];
#pragma unroll
  for (int j = 0; j < 8; ++j) {
    int k = lg * 8 + j;
    if (k < 27) {
      int ci = k / 9, rem = k - ci * 9;
      int r = rem / 3, s = rem - r * 3;
      soff[j] = ci * 360 + r * 20 + s + l15 + w * 80;
    } else {
      soff[j] = 1080;
    }
  }
  __syncthreads();

  f32x4 acc[4][4];
#pragma unroll
  for (int m = 0; m < 4; ++m)
#pragma unroll
    for (int n = 0; n < 4; ++n) acc[m][n] = (f32x4){0.f, 0.f, 0.f, 0.f};

#pragma unroll
  for (int m = 0; m < 4; ++m) {
    union { short8 s; unsigned short u[8]; } af;
#pragma unroll
    for (int j = 0; j < 8; ++j) af.u[j] = tile[soff[j] + m * 20];
#pragma unroll
    for (int n = 0; n < 4; ++n)
      acc[m][n] = __builtin_amdgcn_mfma_f32_16x16x32_bf16(af.s, bf[n], acc[m][n], 0, 0, 0);
  }

#pragma unroll
  for (int n = 0; n < 4; ++n) {
    const int o = n * 16 + l15;
    const float bias = b1[o];
#pragma unroll
    for (int q = 0; q < 2; ++q) {
      const int pr = ty * 8 + w * 2 + q;
      float v0 = fmaxf(fmaxf(acc[2 * q][n][0], acc[2 * q][n][1]),
                       fmaxf(acc[2 * q + 1][n][0], acc[2 * q + 1][n][1]));
      float v1 = fmaxf(fmaxf(acc[2 * q][n][2], acc[2 * q][n][3]),
                       fmaxf(acc[2 * q + 1][n][2], acc[2 * q + 1][n][3]));
      v0 = fmaxf(v0 + bias, 0.f);
      v1 = fmaxf(v1 + bias, 0.f);
      const int pc = tx * 8 + lg * 2;
      unsigned short* dst = y + ((((size_t)b << 6) + pr) << 12) + ((size_t)pc << 6) + o;
      dst[0]  = f2bf(v0);
      dst[64] = f2bf(v1);
    }
  }
}

// ---------------------------------------------------------------------------
// weight reorder for conv2: Bprep[((cg*9+pos)*128 + o)*32 + c] = bf16(w2[o][(cg*32+c)*9 + pos])
// ---------------------------------------------------------------------------
__global__ __launch_bounds__(256) void prep_w2(
    const float* __restrict__ w2, short* __restrict__ Bp) {
  int i = blockIdx.x * 256 + threadIdx.x;   // 73728 total
  int c = i & 31, o = (i >> 5) & 127, pp = i >> 12;
  int cg = pp / 9, pos = pp - cg * 9;
  Bp[i] = (short)f2bf(w2[o * 576 + (cg * 32 + c) * 9 + pos]);
}

// ---------------------------------------------------------------------------
// conv2 v6: software-pipelined implicit-GEMM MFMA.
// block = 256 thr = 4 waves; wave w owns o-range w*32 (2 n-frags) and ALL
// 8 conv rows (2 halves x 4 m-frags): acc[8][2] = 64 VGPR.
// grid 2048 = b x 8 row-tiles x 4 col-tiles; LDS 10x18 x 32ch per cg (14.4 KB)
// -> 4 independent blocks/CU. 18-step k-loop (pos,half), loads for step s+1
// issued BEFORE MFMAs of step s (af dbuf 32 + bf dbuf 16 VGPR).
// ---------------------------------------------------------------------------
__global__ __launch_bounds__(256) void conv2_mfma(
    const short* __restrict__ yin, const short* __restrict__ Bp,
    const float* __restrict__ b2, unsigned int* __restrict__ A32) {
  __shared__ short tile[180 * 40];
  const int t = threadIdx.x;
  const int blk = blockIdx.x;                 // ((b*8 + ty)*4 + tx)
  const int tx = blk & 3, ty = (blk >> 2) & 7, b = blk >> 5;
  const int w = t >> 6, lane = t & 63;
  const int l15 = lane & 15, lg = lane >> 4;

  f32x4 acc[8][2];
#pragma unroll
  for (int m = 0; m < 8; ++m)
#pragma unroll
    for (int n = 0; n < 2; ++n) acc[m][n] = (f32x4){0.f, 0.f, 0.f, 0.f};

  const int ih0 = ty * 8 - 1, iw0 = tx * 16 - 1;
  const int abase = l15 * 40 + lg * 8;        // col offset part of af address

#pragma unroll
  for (int cg = 0; cg < 2; ++cg) {
    __syncthreads();
    // stage 10x18 px x 32 ch of this cg
    for (int i = t; i < 180 * 4; i += 256) {
      int p = i >> 2, q = i & 3;
      int sy = p / 18, sx = p - sy * 18;
      int ih = ih0 + sy, iw = iw0 + sx;
      short8 v = (short8){0, 0, 0, 0, 0, 0, 0, 0};
      if (((unsigned)ih < 64u) && ((unsigned)iw < 64u))
        v = *(const short8*)(yin + ((((size_t)b << 6) + ih) << 12) + ((size_t)iw << 6) + cg * 32 + q * 8);
      *(short8*)&tile[p * 40 + q * 8] = v;
    }
    __syncthreads();

    // pipelined 18-step k-loop: step s = pos*2 + half
    short8 afb[2][4];
    short8 bfb[2][2];

    // prologue: bf(pos=0) -> bfb[0]; af(s=0) -> afb[0]
#pragma unroll
    for (int n = 0; n < 2; ++n)
      bfb[0][n] = *(const short8*)(Bp + ((((cg * 9 + 0) << 7) + (w * 2 + n) * 16 + l15) << 5) + (lg << 3));
#pragma unroll
    for (int m = 0; m < 4; ++m)
      afb[0][m] = *(const short8*)&tile[(m) * 18 * 40 + abase];   // pos0: kh=0,kw=0; half0: row=m

#pragma unroll
    for (int s = 0; s < 18; ++s) {
      const int pos = s >> 1, half = s & 1;
      // issue loads for step s+1 BEFORE this step's MFMAs
      if (s < 17) {
        const int ns = s + 1, npos = ns >> 1, nhalf = ns & 1;
        if (nhalf == 0) {   // new pos -> new bf into bfb[npos&1]
#pragma unroll
          for (int n = 0; n < 2; ++n)
            bfb[npos & 1][n] = *(const short8*)(Bp + ((((cg * 9 + npos) << 7) + (w * 2 + n) * 16 + l15) << 5) + (lg << 3));
        }
        const int nkh = npos / 3, nkw = npos - nkh * 3;
#pragma unroll
        for (int m = 0; m < 4; ++m)
          afb[ns & 1][m] = *(const short8*)&tile[(nhalf * 4 + m + nkh) * 18 * 40 + nkw * 40 + abase];
      }
      // MFMAs of step s
#pragma unroll
      for (int n = 0; n < 2; ++n)
#pragma unroll
        for (int m = 0; m < 4; ++m)
          acc[half * 4 + m][n] = __builtin_amdgcn_mfma_f32_16x16x32_bf16(
              afb[s & 1][m], bfb[pos & 1][n], acc[half * 4 + m][n], 0, 0, 0);
    }
  }

  // epilogue: bias + relu + 2x2 pool. conv row = half*4+m -> pooled mp 0..3;
  // prow = ty*4 + mp; D-row (lg*4+j) = px col -> pooled col pc = tx*8 + lg*2 {+1}.
  const size_t bbase = ((size_t)b << 16);   // u32 units
#pragma unroll
  for (int n = 0; n < 2; ++n) {
    const int o = (w * 2 + n) * 16 + l15;
    const float bias = b2[o];
#pragma unroll
    for (int mp = 0; mp < 4; ++mp) {
      const int prow = ty * 4 + mp;
      float v0 = fmaxf(fmaxf(acc[2 * mp][n][0], acc[2 * mp][n][1]),
                       fmaxf(acc[2 * mp + 1][n][0], acc[2 * mp + 1][n][1]));
      float v1 = fmaxf(fmaxf(acc[2 * mp][n][2], acc[2 * mp][n][3]),
                       fmaxf(acc[2 * mp + 1][n][2], acc[2 * mp + 1][n][3]));
      v0 = fmaxf(v0 + bias, 0.f);
      v1 = fmaxf(v1 + bias, 0.f);
      unsigned pk = (unsigned)f2bf(v0) | ((unsigned)f2bf(v1) << 16);
      A32[bbase + (size_t)o * 512 + prow * 16 + tx * 4 + lg] = pk;
    }
  }
}

// ---------------------------------------------------------------------------
// fc1 MFMA, W streamed direct from global (no LDS round-trip for W):
// grid 512 = kc; block 256 thr = 4 waves; wave = M64 x N64.
// ---------------------------------------------------------------------------
__global__ __launch_bounds__(256) void fc1_mfma(
    const unsigned short* __restrict__ A, const float* __restrict__ W,
    float* __restrict__ P) {
  __shared__ short Al[64][264];
  const int t = threadIdx.x;
  const int kc = blockIdx.x;                  // 0..511
  const int wn = t >> 6, lane = t & 63;
  const int l15 = lane & 15, lg = lane >> 4;

  {
    const int row = t >> 2, q = t & 3;
    const unsigned short* asrc = A + (size_t)row * KFC + kc * 256 + q * 64;
    short8 ar[8];
#pragma unroll
    for (int i = 0; i < 8; ++i) ar[i] = *(const short8*)(asrc + i * 8);
#pragma unroll
    for (int i = 0; i < 8; ++i) *(short8*)&Al[row][q * 64 + i * 8] = ar[i];
  }
  __syncthreads();

  f32x4 acc[4][4];
#pragma unroll
  for (int m = 0; m < 4; ++m)
#pragma unroll
    for (int n = 0; n < 4; ++n) acc[m][n] = (f32x4){0.f, 0.f, 0.f, 0.f};

  const float* wrow[4];
#pragma unroll
  for (int n = 0; n < 4; ++n)
    wrow[n] = W + (size_t)(wn * 64 + n * 16 + l15) * KFC + kc * 256 + lg * 8;

#pragma unroll
  for (int ks = 0; ks < 8; ++ks) {
    short8 bf[4];
#pragma unroll
    for (int n = 0; n < 4; ++n) {
      f32x4 u = *(const f32x4*)(wrow[n] + ks * 32);
      f32x4 v = *(const f32x4*)(wrow[n] + ks * 32 + 4);
      union { short8 s; unsigned u32[4]; } pk;
      pk.u32[0] = pk2bf(u[0], u[1]);
      pk.u32[1] = pk2bf(u[2], u[3]);
      pk.u32[2] = pk2bf(v[0], v[1]);
      pk.u32[3] = pk2bf(v[2], v[3]);
      bf[n] = pk.s;
    }
    short8 af[4];
#pragma unroll
    for (int m = 0; m < 4; ++m)
      af[m] = *(const short8*)&Al[m * 16 + l15][ks * 32 + lg * 8];
#pragma unroll
    for (int n = 0; n < 4; ++n)
#pragma unroll
      for (int m = 0; m < 4; ++m)
        acc[m][n] = __builtin_amdgcn_mfma_f32_16x16x32_bf16(af[m], bf[n], acc[m][n], 0, 0, 0);
  }

  float* dst = P + (size_t)kc * 16384;
#pragma unroll
  for (int m = 0; m < 4; ++m)
#pragma unroll
    for (int n = 0; n < 4; ++n)
#pragma unroll
      for (int j = 0; j < 4; ++j) {
        int brow = m * 16 + lg * 4 + j;
        int o = wn * 64 + n * 16 + l15;
        dst[brow * 256 + o] = acc[m][n][j];
      }
}

// fc1 partial reduce + bias + relu -> Y[64,256]. 256 blocks, coalesced.
__global__ __launch_bounds__(256) void fc1_reduce_kernel(
    const float* __restrict__ P, const float* __restrict__ fb1,
    float* __restrict__ Y) {
  __shared__ float red[4][64];
  const int t = threadIdx.x;
  const int iq = t & 63, pg = t >> 6;
  const int gidx = blockIdx.x * 64 + iq;
  const float* p0 = P + (size_t)(pg * 128) * 16384 + gidx;
  float s0 = 0, s1 = 0, s2 = 0, s3 = 0;
  for (int p = 0; p < 128; p += 4) {
    s0 += p0[(size_t)(p + 0) * 16384];
    s1 += p0[(size_t)(p + 1) * 16384];
    s2 += p0[(size_t)(p + 2) * 16384];
    s3 += p0[(size_t)(p + 3) * 16384];
  }
  red[pg][iq] = (s0 + s1) + (s2 + s3);
  __syncthreads();
  if (pg == 0) {
    float tot = (red[0][iq] + red[1][iq]) + (red[2][iq] + red[3][iq]);
    Y[gidx] = fmaxf(tot + fb1[gidx & 255], 0.f);
  }
}

// fc2: out[64,1000] = Y[64,256] @ W2[1000,256]^T + b2
__global__ __launch_bounds__(256) void fc2_kernel(
    const float* __restrict__ Y, const float* __restrict__ W2,
    const float* __restrict__ b2, float* __restrict__ out) {
  int tid = blockIdx.x * 256 + threadIdx.x;
  if (tid >= 64 * NCLS) return;
  int b = tid / NCLS, n = tid - b * NCLS;
  const float4* yv = (const float4*)(Y + b * 256);
  const float4* wv = (const float4*)(W2 + n * 256);
  float acc = 0.f;
#pragma unroll 8
  for (int f = 0; f < 64; ++f) {
    float4 a = yv[f], w = wv[f];
    acc += a.x * w.x + a.y * w.y + a.z * w.z + a.w * w.w;
  }
  out[tid] = acc + b2[n];
}

// ---------------------------------------------------------------------------
extern "C" void kernel_launch(void* const* d_in, const int* in_sizes, int n_in,
                              void* d_out, int out_size, void* d_ws, size_t ws_size,
                              hipStream_t stream) {
  const float* x   = (const float*)d_in[0];
  const float* w1  = (const float*)d_in[1];
  const float* b1  = (const float*)d_in[2];
  const float* w2  = (const float*)d_in[3];
  const float* b2  = (const float*)d_in[4];
  const float* fw1 = (const float*)d_in[5];
  const float* fb1 = (const float*)d_in[6];
  const float* fw2 = (const float*)d_in[7];
  const float* fb2 = (const float*)d_in[8];
  float* out = (float*)d_out;

  unsigned short* Y1 = (unsigned short*)d_ws;              // conv1 out bf16 NHWC [16777216]
  unsigned short* A16 = Y1 + 16777216;                     // conv2 out bf16 [8388608]
  short* Bp = (short*)(A16 + 8388608);                     // conv2 weights bf16 [73728]
  short* Bp1 = Bp + 73728;                                 // conv1 weights bf16 [2048]
  float* P  = (float*)(Bp1 + 2048);                        // fc1 partials [512*16384]
  float* Yf = P + 8388608;                                 // fc1 out [16384]

  prep_w2<<<288, 256, 0, stream>>>(w2, Bp);
  prep_w1<<<8, 256, 0, stream>>>(w1, Bp1);
  conv1_mfma<<<4096, 256, 0, stream>>>(x, Bp1, b1, Y1);
  conv2_mfma<<<2048, 256, 0, stream>>>((const short*)Y1, Bp, b2, (unsigned int*)A16);
  fc1_mfma<<<512, 256, 0, stream>>>(A16, fw1, P);
  fc1_reduce_kernel<<<256, 256, 0, stream>>>(P, fb1, Yf);
  fc2_kernel<<<250, 256, 0, stream>>>(Yf, fw2, fb2, out);
}